// Round 1
// baseline (1512.169 us; speedup 1.0000x reference)
//
#include <hip/hip_runtime.h>

#define B_ 8
#define C_ 512
#define N_ 16384
#define R_ 64
#define EPS 1e-6f

typedef float  f32x4  __attribute__((ext_vector_type(4)));
typedef short  bf16x4 __attribute__((ext_vector_type(4)));
typedef short  bf16x8 __attribute__((ext_vector_type(8)));

#define DI __device__ __forceinline__

DI short f2bf(float f) {
    union { float f; unsigned u; } a; a.f = f;
    unsigned r = a.u + 0x7fffu + ((a.u >> 16) & 1u);
    return (short)(r >> 16);
}
DI float bf2f(short s) {
    union { unsigned u; float f; } a;
    a.u = ((unsigned)(unsigned short)s) << 16;
    return a.f;
}

union BV { bf16x8 v; bf16x4 h[2]; };
DI bf16x8 ldfrag(const short* p) {
    BV u;
    u.h[0] = *(const bf16x4*)p;
    u.h[1] = *(const bf16x4*)(p + 4);
    return u.v;
}
DI f32x4 mfma16(bf16x8 a, bf16x8 b, f32x4 c) {
    return __builtin_amdgcn_mfma_f32_16x16x32_bf16(a, b, c, 0, 0, 0);
}

// ---------------------------------------------------------------------------
// prep: bases [512][64] f32  ->  basesT [8][64][512] f32 + bf16 copy
// ---------------------------------------------------------------------------
__global__ __launch_bounds__(256)
void k_prep(const float* __restrict__ bases, float* __restrict__ basesT,
            short* __restrict__ basesTb) {
    int idx = blockIdx.x * 256 + threadIdx.x;        // 8*64*512 = 262144
    const int d = idx & 511;
    const int r = (idx >> 9) & 63;
    const float v = bases[d * 64 + r];
    basesT[idx]  = v;
    basesTb[idx] = f2bf(v);
}

// ---------------------------------------------------------------------------
// conv1: H = relu(Win @ X + b_in)   (per batch: [512,512]@[512,16384])
// tile 128x128, BK=32, 256 thr (2x2 waves of 64x64)
// ---------------------------------------------------------------------------
__global__ __launch_bounds__(256)
void k_conv1(const float* __restrict__ W, const float* __restrict__ bias,
             const float* __restrict__ X, short* __restrict__ H) {
    const int nb = blockIdx.x * 128, mb = blockIdx.y * 128, bb = blockIdx.z;
    const float* Xb = X + (size_t)bb * C_ * N_;
    short* Hb = H + (size_t)bb * C_ * N_;
    __shared__ short As[128 * 36];
    __shared__ short Bs[128 * 36];
    const int t = threadIdx.x;
    const int lane = t & 63, wave = t >> 6;
    const int wm = wave >> 1, wn = wave & 1;
    const int fr = lane & 15, fg = lane >> 4;
    f32x4 zero4 = {0.f, 0.f, 0.f, 0.f};
    f32x4 acc[4][4];
    for (int i = 0; i < 4; i++) for (int j = 0; j < 4; j++) acc[i][j] = zero4;

    for (int kb = 0; kb < C_; kb += 32) {
        {   // stage A (Win f32 -> bf16), row-major k-contig
            const int row = t >> 1, kh = (t & 1) * 16;
            const float* src = W + (size_t)(mb + row) * C_ + kb + kh;
            short* dst = &As[row * 36 + kh];
#pragma unroll
            for (int i = 0; i < 4; i++) {
                float4 v = *(const float4*)(src + 4 * i);
                bf16x4 s; s[0]=f2bf(v.x); s[1]=f2bf(v.y); s[2]=f2bf(v.z); s[3]=f2bf(v.w);
                *(bf16x4*)(dst + 4 * i) = s;
            }
        }
        {   // stage B transposed: X[k][n] -> Bs[n*36+k] (pack 2 k's per u32)
            const int n0 = (t & 31) * 4;
#pragma unroll
            for (int i = 0; i < 2; i++) {
                const int kp = (t >> 5) + 8 * i, k = 2 * kp;
                const float* r0 = Xb + (size_t)(kb + k) * N_ + nb + n0;
                float4 va = *(const float4*)r0;
                float4 vb = *(const float4*)(r0 + N_);
                const float* pa = (const float*)&va;
                const float* pb = (const float*)&vb;
#pragma unroll
                for (int j = 0; j < 4; j++) {
                    unsigned lo = (unsigned short)f2bf(pa[j]);
                    unsigned hi = (unsigned short)f2bf(pb[j]);
                    *(unsigned*)&Bs[(n0 + j) * 36 + k] = lo | (hi << 16);
                }
            }
        }
        __syncthreads();
        bf16x8 af[4], bv[4];
#pragma unroll
        for (int mi = 0; mi < 4; mi++) af[mi] = ldfrag(&As[(wm * 64 + mi * 16 + fr) * 36 + fg * 8]);
#pragma unroll
        for (int ni = 0; ni < 4; ni++) bv[ni] = ldfrag(&Bs[(wn * 64 + ni * 16 + fr) * 36 + fg * 8]);
#pragma unroll
        for (int mi = 0; mi < 4; mi++)
#pragma unroll
            for (int ni = 0; ni < 4; ni++)
                acc[mi][ni] = mfma16(af[mi], bv[ni], acc[mi][ni]);
        __syncthreads();
    }
#pragma unroll
    for (int mi = 0; mi < 4; mi++) {
#pragma unroll
        for (int j = 0; j < 4; j++) {
            const int m = mb + wm * 64 + mi * 16 + fg * 4 + j;
            const float bvv = bias[m];
            short* orow = Hb + (size_t)m * N_ + nb;
#pragma unroll
            for (int ni = 0; ni < 4; ni++) {
                float v = acc[mi][ni][j] + bvv;
                v = v > 0.f ? v : 0.f;
                orow[wn * 64 + ni * 16 + fr] = f2bf(v);
            }
        }
    }
}

// ---------------------------------------------------------------------------
// k_coef: fused coef update.  num = basesT @ H (K=512); if UPDATE: den = btb @ coef
// (K=64), coef *= num/(den+eps); else coef = softmax_r(num).
// tile M=64 x N=256, 4 waves each own 64 columns.
// ---------------------------------------------------------------------------
template<int UPDATE>
__global__ __launch_bounds__(256)
void k_coef(const short* __restrict__ basesTb, const short* __restrict__ Hh,
            const short* __restrict__ btb, short* __restrict__ coef) {
    const int nb = blockIdx.x * 256, bb = blockIdx.y;
    const short* Hb = Hh + (size_t)bb * C_ * N_;
    const short* bT = basesTb + (size_t)bb * R_ * C_;
    short* coefB = coef + (size_t)bb * R_ * N_;
    __shared__ short As[64 * 36];
    __shared__ short Bs[256 * 36];
    __shared__ short Ds[64 * 68];
    const int t = threadIdx.x;
    const int lane = t & 63, wave = t >> 6;
    const int fr = lane & 15, fg = lane >> 4;
    f32x4 zero4 = {0.f, 0.f, 0.f, 0.f};
    f32x4 accN[4][4];
    for (int i = 0; i < 4; i++) for (int j = 0; j < 4; j++) accN[i][j] = zero4;

    // phase 1: num = basesT @ H
    for (int kb = 0; kb < C_; kb += 32) {
        {   // A: basesT bf16 [64][512], copy 8 shorts/thread
            const int row = t >> 2, kc = (t & 3) * 8;
            const short* src = bT + row * C_ + kb + kc;
            short* dst = &As[row * 36 + kc];
            *(bf16x4*)dst = *(const bf16x4*)src;
            *(bf16x4*)(dst + 4) = *(const bf16x4*)(src + 4);
        }
        {   // B transposed: H[k][n] -> Bs[n*36+k]
            const int n0 = (t & 63) * 4;
#pragma unroll
            for (int i = 0; i < 4; i++) {
                const int kp = (t >> 6) + 4 * i, k = 2 * kp;
                const short* r0 = Hb + (size_t)(kb + k) * N_ + nb + n0;
                bf16x4 a = *(const bf16x4*)r0;
                bf16x4 b = *(const bf16x4*)(r0 + N_);
#pragma unroll
                for (int j = 0; j < 4; j++)
                    *(unsigned*)&Bs[(n0 + j) * 36 + k] =
                        (unsigned)(unsigned short)a[j] | ((unsigned)(unsigned short)b[j] << 16);
            }
        }
        __syncthreads();
        bf16x8 af[4], bv[4];
#pragma unroll
        for (int mi = 0; mi < 4; mi++) af[mi] = ldfrag(&As[(mi * 16 + fr) * 36 + fg * 8]);
#pragma unroll
        for (int ni = 0; ni < 4; ni++) bv[ni] = ldfrag(&Bs[(wave * 64 + ni * 16 + fr) * 36 + fg * 8]);
#pragma unroll
        for (int mi = 0; mi < 4; mi++)
#pragma unroll
            for (int ni = 0; ni < 4; ni++)
                accN[mi][ni] = mfma16(af[mi], bv[ni], accN[mi][ni]);
        __syncthreads();
    }

    f32x4 accD[4][4];
    if (UPDATE) {
        for (int i = 0; i < 4; i++) for (int j = 0; j < 4; j++) accD[i][j] = zero4;
        {   // stage btb [64][64] -> Ds (stride 68)
            const short* bt = btb + bb * R_ * R_;
#pragma unroll
            for (int i = 0; i < 2; i++) {
                const int row = t & 63, kc8 = ((t >> 6) + 4 * i) * 8;
                const short* src = bt + row * 64 + kc8;
                short* dst = &Ds[row * 68 + kc8];
                *(bf16x4*)dst = *(const bf16x4*)src;
                *(bf16x4*)(dst + 4) = *(const bf16x4*)(src + 4);
            }
        }
        // phase 2: den = btb @ coef, two K=32 substeps reusing Bs
        for (int ks = 0; ks < 2; ks++) {
            const int n0 = (t & 63) * 4;
#pragma unroll
            for (int i = 0; i < 4; i++) {
                const int kp = (t >> 6) + 4 * i, k = 2 * kp;
                const short* r0 = coefB + (size_t)(ks * 32 + k) * N_ + nb + n0;
                bf16x4 a = *(const bf16x4*)r0;
                bf16x4 b = *(const bf16x4*)(r0 + N_);
#pragma unroll
                for (int j = 0; j < 4; j++)
                    *(unsigned*)&Bs[(n0 + j) * 36 + k] =
                        (unsigned)(unsigned short)a[j] | ((unsigned)(unsigned short)b[j] << 16);
            }
            __syncthreads();
            bf16x8 af[4], bv[4];
#pragma unroll
            for (int mi = 0; mi < 4; mi++) af[mi] = ldfrag(&Ds[(mi * 16 + fr) * 68 + ks * 32 + fg * 8]);
#pragma unroll
            for (int ni = 0; ni < 4; ni++) bv[ni] = ldfrag(&Bs[(wave * 64 + ni * 16 + fr) * 36 + fg * 8]);
#pragma unroll
            for (int mi = 0; mi < 4; mi++)
#pragma unroll
                for (int ni = 0; ni < 4; ni++)
                    accD[mi][ni] = mfma16(af[mi], bv[ni], accD[mi][ni]);
            __syncthreads();
        }
        // phase 3: multiplicative update (read-modify-write own element)
#pragma unroll
        for (int mi = 0; mi < 4; mi++)
#pragma unroll
            for (int ni = 0; ni < 4; ni++)
#pragma unroll
                for (int j = 0; j < 4; j++) {
                    const int m = mi * 16 + fg * 4 + j;
                    const int n = nb + wave * 64 + ni * 16 + fr;
                    short* p = coefB + (size_t)m * N_ + n;
                    float oldv = bf2f(*p);
                    float nv = oldv * accN[mi][ni][j] / (accD[mi][ni][j] + EPS);
                    *p = f2bf(nv);
                }
    } else {
        // softmax over r (64 rows) per column; column data lives in lanes {fr, fr^16,...} x (mi,j)
#pragma unroll
        for (int ni = 0; ni < 4; ni++) {
            float mx = -3e38f;
#pragma unroll
            for (int mi = 0; mi < 4; mi++)
#pragma unroll
                for (int j = 0; j < 4; j++) mx = fmaxf(mx, accN[mi][ni][j]);
            mx = fmaxf(mx, __shfl_xor(mx, 16, 64));
            mx = fmaxf(mx, __shfl_xor(mx, 32, 64));
            float sm = 0.f;
#pragma unroll
            for (int mi = 0; mi < 4; mi++)
#pragma unroll
                for (int j = 0; j < 4; j++) {
                    float e = __expf(accN[mi][ni][j] - mx);
                    accN[mi][ni][j] = e;
                    sm += e;
                }
            sm += __shfl_xor(sm, 16, 64);
            sm += __shfl_xor(sm, 32, 64);
            const float inv = 1.f / sm;
#pragma unroll
            for (int mi = 0; mi < 4; mi++)
#pragma unroll
                for (int j = 0; j < 4; j++) {
                    const int m = mi * 16 + fg * 4 + j;
                    const int n = nb + wave * 64 + ni * 16 + fr;
                    coefB[(size_t)m * N_ + n] = f2bf(accN[mi][ni][j] * inv);
                }
        }
    }
}

// ---------------------------------------------------------------------------
// k_tn: C[r][dd] = sum_k A[r,k]*B[dd,k]  (both K-contiguous; TN GEMM)
// MODE 0: A=coef, B=[H ; coef] rows (576), split-K -> f32 partials
// MODE 1: A=B=basesT  -> btb bf16
// MODE 2: A=basesT, B=Wout(f32) -> Wfused bf16 stored [o][r]
// ---------------------------------------------------------------------------
template<int MODE>
__global__ __launch_bounds__(256)
void k_tn(const short* __restrict__ coef, const short* __restrict__ Hh,
          const short* __restrict__ basesTb, const float* __restrict__ Wout,
          float* __restrict__ parts, short* __restrict__ btb, short* __restrict__ wf) {
    const int ddt = blockIdx.x, ch = blockIdx.y, bb = blockIdx.z;
    const int kLen = (MODE == 0) ? 2048 : 512;
    const int k0g = ch * kLen;
    const short* Ap; int lda;
    if (MODE == 0) { Ap = coef + (size_t)bb * R_ * N_; lda = N_; }
    else           { Ap = basesTb + (size_t)bb * R_ * C_; lda = C_; }
    __shared__ short As[64 * 72];
    __shared__ short Bs[64 * 72];
    const int t = threadIdx.x;
    const int lane = t & 63, wave = t >> 6;
    const int fr = lane & 15, fg = lane >> 4;
    f32x4 zero4 = {0.f, 0.f, 0.f, 0.f};
    f32x4 acc[4];
    for (int i = 0; i < 4; i++) acc[i] = zero4;

    for (int kb = 0; kb < kLen; kb += 64) {
#pragma unroll
        for (int i = 0; i < 2; i++) {   // stage A
            const int kg = (t & 7) * 8, row = (t >> 3) + 32 * i;
            const short* src = Ap + (size_t)row * lda + k0g + kb + kg;
            short* dst = &As[row * 72 + kg];
            *(bf16x4*)dst = *(const bf16x4*)src;
            *(bf16x4*)(dst + 4) = *(const bf16x4*)(src + 4);
        }
#pragma unroll
        for (int i = 0; i < 2; i++) {   // stage B
            const int kg = (t & 7) * 8, row = (t >> 3) + 32 * i;
            const int dd = ddt * 64 + row;
            short* dst = &Bs[row * 72 + kg];
            if (MODE == 2) {
                const float* src = Wout + (size_t)dd * C_ + kb + kg;
                float4 v0 = *(const float4*)src;
                float4 v1 = *(const float4*)(src + 4);
                bf16x4 s0, s1;
                s0[0]=f2bf(v0.x); s0[1]=f2bf(v0.y); s0[2]=f2bf(v0.z); s0[3]=f2bf(v0.w);
                s1[0]=f2bf(v1.x); s1[1]=f2bf(v1.y); s1[2]=f2bf(v1.z); s1[3]=f2bf(v1.w);
                *(bf16x4*)dst = s0; *(bf16x4*)(dst + 4) = s1;
            } else {
                const short* src;
                if (MODE == 0)
                    src = (dd < C_) ? Hh + (size_t)bb * C_ * N_ + (size_t)dd * N_ + k0g + kb + kg
                                    : coef + (size_t)bb * R_ * N_ + (size_t)(dd - C_) * N_ + k0g + kb + kg;
                else
                    src = basesTb + (size_t)bb * R_ * C_ + (size_t)dd * C_ + kb + kg;
                *(bf16x4*)dst = *(const bf16x4*)src;
                *(bf16x4*)(dst + 4) = *(const bf16x4*)(src + 4);
            }
        }
        __syncthreads();
#pragma unroll
        for (int kk = 0; kk < 2; kk++) {
            bf16x8 a = ldfrag(&As[(wave * 16 + fr) * 72 + kk * 32 + fg * 8]);
#pragma unroll
            for (int ni = 0; ni < 4; ni++) {
                bf16x8 b = ldfrag(&Bs[(ni * 16 + fr) * 72 + kk * 32 + fg * 8]);
                acc[ni] = mfma16(a, b, acc[ni]);
            }
        }
        __syncthreads();
    }
#pragma unroll
    for (int ni = 0; ni < 4; ni++)
#pragma unroll
        for (int j = 0; j < 4; j++) {
            const int r = wave * 16 + fg * 4 + j;
            const int dd = ddt * 64 + ni * 16 + fr;
            if (MODE == 0)
                parts[(((size_t)bb * 8 + ch) * 64 + r) * 576 + dd] = acc[ni][j];
            else if (MODE == 1)
                btb[bb * R_ * R_ + r * 64 + dd] = f2bf(acc[ni][j]);
            else
                wf[(size_t)bb * C_ * R_ + (size_t)dd * 64 + r] = f2bf(acc[ni][j]);
        }
}

// ---------------------------------------------------------------------------
// k_bases_update: ctc = sum(parts[:, :, 512:576]); num2 = sum(parts[:, :, d]);
// den2 = ctc @ basesT; basesT *= num2/(den2+eps)
// grid (8 d-tiles, 8 batches)
// ---------------------------------------------------------------------------
__global__ __launch_bounds__(256)
void k_bases_update(const float* __restrict__ parts, float* __restrict__ basesT,
                    short* __restrict__ basesTb) {
    const int dt = blockIdx.x, bb = blockIdx.y;
    __shared__ float ctcL[64 * 64];
    const int t = threadIdx.x;
    for (int idx = t; idx < 4096; idx += 256) {
        const int r = idx >> 6, s = idx & 63;
        float sum = 0.f;
#pragma unroll
        for (int ch = 0; ch < 8; ch++)
            sum += parts[(((size_t)bb * 8 + ch) * 64 + r) * 576 + 512 + s];
        ctcL[idx] = sum;
    }
    __syncthreads();
    float nv[16];
#pragma unroll
    for (int i = 0; i < 16; i++) {
        const int idx = t + i * 256;
        const int r = idx >> 6, d = dt * 64 + (idx & 63);
        float num = 0.f;
#pragma unroll
        for (int ch = 0; ch < 8; ch++)
            num += parts[(((size_t)bb * 8 + ch) * 64 + r) * 576 + d];
        float den = 0.f;
        const float* bcol = basesT + (size_t)bb * R_ * C_ + d;
        for (int s = 0; s < 64; s++)
            den += ctcL[r * 64 + s] * bcol[(size_t)s * C_];
        const float oldv = basesT[(size_t)bb * R_ * C_ + (size_t)r * C_ + d];
        nv[i] = oldv * num / (den + EPS);
    }
    __syncthreads();
#pragma unroll
    for (int i = 0; i < 16; i++) {
        const int idx = t + i * 256;
        const int r = idx >> 6, d = dt * 64 + (idx & 63);
        basesT[(size_t)bb * R_ * C_ + (size_t)r * C_ + d] = nv[i];
        basesTb[(size_t)bb * R_ * C_ + (size_t)r * C_ + d] = f2bf(nv[i]);
    }
}

// ---------------------------------------------------------------------------
// k_final: out = relu(x + Wfused @ coef + b_out)   (K=64)
// tile 128x128, single K stage
// ---------------------------------------------------------------------------
__global__ __launch_bounds__(256)
void k_final(const short* __restrict__ wf, const short* __restrict__ coef,
             const float* __restrict__ X, const float* __restrict__ bias,
             float* __restrict__ out) {
    const int nb = blockIdx.x * 128, mb = blockIdx.y * 128, bb = blockIdx.z;
    __shared__ short As[128 * 72];
    __shared__ short Bs[128 * 72];
    const int t = threadIdx.x;
    const int lane = t & 63, wave = t >> 6;
    const int wm = wave >> 1, wn = wave & 1;
    const int fr = lane & 15, fg = lane >> 4;
    const short* wfb = wf + (size_t)bb * C_ * R_;
    const short* coefB = coef + (size_t)bb * R_ * N_;
    f32x4 zero4 = {0.f, 0.f, 0.f, 0.f};
    f32x4 acc[4][4];
    for (int i = 0; i < 4; i++) for (int j = 0; j < 4; j++) acc[i][j] = zero4;

#pragma unroll
    for (int i = 0; i < 4; i++) {   // stage A = Wfused [128 rows][64]
        const int kg = (t & 7) * 8, row = (t >> 3) + 32 * i;
        const short* src = wfb + (size_t)(mb + row) * 64 + kg;
        short* dst = &As[row * 72 + kg];
        *(bf16x4*)dst = *(const bf16x4*)src;
        *(bf16x4*)(dst + 4) = *(const bf16x4*)(src + 4);
    }
    {   // stage B transposed: coef[k][n] -> Bs[n*72+k]
        const int n0 = (t & 31) * 4;
#pragma unroll
        for (int i = 0; i < 4; i++) {
            const int kp = (t >> 5) + 8 * i, k = 2 * kp;
            const short* r0 = coefB + (size_t)k * N_ + nb + n0;
            bf16x4 a = *(const bf16x4*)r0;
            bf16x4 b = *(const bf16x4*)(r0 + N_);
#pragma unroll
            for (int j = 0; j < 4; j++)
                *(unsigned*)&Bs[(n0 + j) * 72 + k] =
                    (unsigned)(unsigned short)a[j] | ((unsigned)(unsigned short)b[j] << 16);
        }
    }
    __syncthreads();
#pragma unroll
    for (int kk = 0; kk < 2; kk++) {
        bf16x8 af[4], bv[4];
#pragma unroll
        for (int mi = 0; mi < 4; mi++) af[mi] = ldfrag(&As[(wm * 64 + mi * 16 + fr) * 72 + kk * 32 + fg * 8]);
#pragma unroll
        for (int ni = 0; ni < 4; ni++) bv[ni] = ldfrag(&Bs[(wn * 64 + ni * 16 + fr) * 72 + kk * 32 + fg * 8]);
#pragma unroll
        for (int mi = 0; mi < 4; mi++)
#pragma unroll
            for (int ni = 0; ni < 4; ni++)
                acc[mi][ni] = mfma16(af[mi], bv[ni], acc[mi][ni]);
    }
    const float* Xb = X + (size_t)bb * C_ * N_;
    float* Ob = out + (size_t)bb * C_ * N_;
#pragma unroll
    for (int mi = 0; mi < 4; mi++)
#pragma unroll
        for (int j = 0; j < 4; j++) {
            const int m = mb + wm * 64 + mi * 16 + fg * 4 + j;
            const float bvv = bias[m];
            const float* xrow = Xb + (size_t)m * N_ + nb;
            float* orow = Ob + (size_t)m * N_ + nb;
#pragma unroll
            for (int ni = 0; ni < 4; ni++) {
                const int n = wn * 64 + ni * 16 + fr;
                float v = xrow[n] + acc[mi][ni][j] + bvv;
                orow[n] = v > 0.f ? v : 0.f;
            }
        }
}

// ---------------------------------------------------------------------------
extern "C" void kernel_launch(void* const* d_in, const int* in_sizes, int n_in,
                              void* d_out, int out_size, void* d_ws, size_t ws_size,
                              hipStream_t stream) {
    const float* x     = (const float*)d_in[0];
    const float* w_in  = (const float*)d_in[1];
    const float* b_in  = (const float*)d_in[2];
    const float* w_out = (const float*)d_in[3];
    const float* b_out = (const float*)d_in[4];
    const float* bases = (const float*)d_in[5];
    float* out = (float*)d_out;

    short* h       = (short*)d_ws;                     // 67108864 shorts (134.2 MB)
    short* coef    = h + (size_t)67108864;             // 8388608 shorts (16.8 MB)
    float* basesT  = (float*)(coef + 8388608);         // 262144 floats (1 MB)
    short* basesTb = (short*)(basesT + 262144);        // 262144 shorts
    short* btb     = basesTb + 262144;                 // 32768 shorts
    short* wf      = btb + 32768;                      // 262144 shorts
    float* parts   = (float*)(wf + 262144);            // 2359296 floats (9.4 MB)

    k_prep<<<1024, 256, 0, stream>>>(bases, basesT, basesTb);
    k_conv1<<<dim3(128, 4, 8), 256, 0, stream>>>(w_in, b_in, x, h);
    k_coef<0><<<dim3(64, 8), 256, 0, stream>>>(basesTb, h, btb, coef);
    for (int s = 0; s < 7; s++) {
        k_tn<1><<<dim3(1, 1, 8), 256, 0, stream>>>(coef, h, basesTb, w_out, parts, btb, wf);
        k_coef<1><<<dim3(64, 8), 256, 0, stream>>>(basesTb, h, btb, coef);
        k_tn<0><<<dim3(9, 8, 8), 256, 0, stream>>>(coef, h, basesTb, w_out, parts, btb, wf);
        k_bases_update<<<dim3(8, 8), 256, 0, stream>>>(parts, basesT, basesTb);
    }
    k_tn<1><<<dim3(1, 1, 8), 256, 0, stream>>>(coef, h, basesTb, w_out, parts, btb, wf);
    k_coef<1><<<dim3(64, 8), 256, 0, stream>>>(basesTb, h, btb, coef);
    k_tn<2><<<dim3(8, 1, 8), 256, 0, stream>>>(coef, h, basesTb, w_out, parts, btb, wf);
    k_final<<<dim3(128, 4, 8), 256, 0, stream>>>(wf, coef, x, b_out, out);
}

// Round 2
// 1473.492 us; speedup vs baseline: 1.0262x; 1.0262x over previous
//
#include <hip/hip_runtime.h>
#include <hip/hip_bf16.h>

#define B_ 8
#define C_ 512
#define N_ 16384
#define R_ 64
#define EPS 1e-6f

typedef float  f32x4  __attribute__((ext_vector_type(4)));
typedef short  bf16x4 __attribute__((ext_vector_type(4)));
typedef short  bf16x8 __attribute__((ext_vector_type(8)));

#define DI __device__ __forceinline__

DI short f2bf(float f) {
    union { float f; unsigned u; } a; a.f = f;
    unsigned r = a.u + 0x7fffu + ((a.u >> 16) & 1u);
    return (short)(r >> 16);
}
DI float bf2f(short s) {
    union { unsigned u; float f; } a;
    a.u = ((unsigned)(unsigned short)s) << 16;
    return a.f;
}
DI unsigned pk2(float lo, float hi) {
    union { __hip_bfloat162 h; unsigned u; } c;
    c.h = __float22bfloat162_rn(make_float2(lo, hi));
    return c.u;
}

union BV { bf16x8 v; bf16x4 h[2]; };
DI bf16x8 ldfrag(const short* p) {
    BV u;
    u.h[0] = *(const bf16x4*)p;
    u.h[1] = *(const bf16x4*)(p + 4);
    return u.v;
}
DI f32x4 mfma16(bf16x8 a, bf16x8 b, f32x4 c) {
    return __builtin_amdgcn_mfma_f32_16x16x32_bf16(a, b, c, 0, 0, 0);
}

// ---------------------------------------------------------------------------
// prep: bases [512][64] f32 -> basesT [8][64][512] f32 + bf16; w_in -> bf16
// ---------------------------------------------------------------------------
__global__ __launch_bounds__(256)
void k_prep(const float* __restrict__ bases, float* __restrict__ basesT,
            short* __restrict__ basesTb, const float* __restrict__ w_in,
            short* __restrict__ wbf) {
    int idx = blockIdx.x * 256 + threadIdx.x;        // 262144
    const int d = idx & 511;
    const int r = (idx >> 9) & 63;
    const float v = bases[d * 64 + r];
    basesT[idx]  = v;
    basesTb[idx] = f2bf(v);
    wbf[idx] = f2bf(w_in[idx]);                      // w_in also 512*512
}

// ---------------------------------------------------------------------------
// conv1: H = relu(Win @ X + b_in)   (per batch: [512,512]@[512,16384])
// tile 128x128, BK=32, 256 thr (2x2 waves of 64x64)
// ---------------------------------------------------------------------------
__global__ __launch_bounds__(256)
void k_conv1(const short* __restrict__ Wbf, const float* __restrict__ bias,
             const float* __restrict__ X, short* __restrict__ H) {
    const int nb = blockIdx.x * 128, mb = blockIdx.y * 128, bb = blockIdx.z;
    const float* Xb = X + (size_t)bb * C_ * N_;
    short* Hb = H + (size_t)bb * C_ * N_;
    __shared__ short As[128 * 36];
    __shared__ short Bs[128 * 36];
    const int t = threadIdx.x;
    const int lane = t & 63, wave = t >> 6;
    const int wm = wave >> 1, wn = wave & 1;
    const int fr = lane & 15, fg = lane >> 4;
    f32x4 zero4 = {0.f, 0.f, 0.f, 0.f};
    f32x4 acc[4][4];
    for (int i = 0; i < 4; i++) for (int j = 0; j < 4; j++) acc[i][j] = zero4;

    // staging assignments (hoisted)
    const int an_row = t >> 2, an_kc = (t & 3) * 8;          // A copy
    const int bn = t & 15, bkp = t >> 4;                     // B transpose

    for (int kb = 0; kb < C_; kb += 32) {
        {   // stage A: copy Wbf (bf16) rows, k-contig
#pragma unroll
            for (int i = 0; i < 2; i++) {
                const int row = an_row + 64 * i;
                const short* src = Wbf + (size_t)(mb + row) * C_ + kb + an_kc;
                short* dst = &As[row * 36 + an_kc];
                *(bf16x4*)dst = *(const bf16x4*)src;
                *(bf16x4*)(dst + 4) = *(const bf16x4*)(src + 4);
            }
        }
        {   // stage B transposed: X[k][n] -> Bs[n*36+k]; lane owns (n=bn+16p, k=2*bkp)
            const float* r0 = Xb + (size_t)(kb + 2 * bkp) * N_ + nb + bn;
#pragma unroll
            for (int p = 0; p < 8; p++) {
                const float va = r0[16 * p];
                const float vb = r0[16 * p + N_];
                *(unsigned*)&Bs[(bn + 16 * p) * 36 + 2 * bkp] = pk2(va, vb);
            }
        }
        __syncthreads();
        bf16x8 af[4], bv[4];
#pragma unroll
        for (int mi = 0; mi < 4; mi++) af[mi] = ldfrag(&As[(wm * 64 + mi * 16 + fr) * 36 + fg * 8]);
#pragma unroll
        for (int ni = 0; ni < 4; ni++) bv[ni] = ldfrag(&Bs[(wn * 64 + ni * 16 + fr) * 36 + fg * 8]);
#pragma unroll
        for (int mi = 0; mi < 4; mi++)
#pragma unroll
            for (int ni = 0; ni < 4; ni++)
                acc[mi][ni] = mfma16(af[mi], bv[ni], acc[mi][ni]);
        __syncthreads();
    }
#pragma unroll
    for (int mi = 0; mi < 4; mi++) {
#pragma unroll
        for (int j = 0; j < 4; j++) {
            const int m = mb + wm * 64 + mi * 16 + fg * 4 + j;
            const float bvv = bias[m];
            short* orow = Hb + (size_t)m * N_ + nb;
#pragma unroll
            for (int ni = 0; ni < 4; ni++) {
                float v = acc[mi][ni][j] + bvv;
                v = v > 0.f ? v : 0.f;
                orow[wn * 64 + ni * 16 + fr] = f2bf(v);
            }
        }
    }
}

// ---------------------------------------------------------------------------
// k_coef: fused coef update.  num = basesT @ H (K=512); if UPDATE: den = btb @ coef
// (K=64), coef *= num/(den+eps); else coef = softmax_r(num).
// ---------------------------------------------------------------------------
template<int UPDATE>
__global__ __launch_bounds__(256)
void k_coef(const short* __restrict__ basesTb, const short* __restrict__ Hh,
            const short* __restrict__ btb, short* __restrict__ coef) {
    const int nb = blockIdx.x * 256, bb = blockIdx.y;
    const short* Hb = Hh + (size_t)bb * C_ * N_;
    const short* bT = basesTb + (size_t)bb * R_ * C_;
    short* coefB = coef + (size_t)bb * R_ * N_;
    __shared__ short As[64 * 36];
    __shared__ short Bs[256 * 36];
    __shared__ short Ds[64 * 68];
    const int t = threadIdx.x;
    const int lane = t & 63, wave = t >> 6;
    const int fr = lane & 15, fg = lane >> 4;
    f32x4 zero4 = {0.f, 0.f, 0.f, 0.f};
    f32x4 accN[4][4];
    for (int i = 0; i < 4; i++) for (int j = 0; j < 4; j++) accN[i][j] = zero4;

    const int bn = 2 * (t & 15), bkp = t >> 4;   // B transpose lanes: pair of n, k=2*bkp

    // phase 1: num = basesT @ H
    for (int kb = 0; kb < C_; kb += 32) {
        {   // A: basesT bf16 copy
            const int row = t >> 2, kc = (t & 3) * 8;
            const short* src = bT + row * C_ + kb + kc;
            short* dst = &As[row * 36 + kc];
            *(bf16x4*)dst = *(const bf16x4*)src;
            *(bf16x4*)(dst + 4) = *(const bf16x4*)(src + 4);
        }
        {   // B transposed: H[k][n] -> Bs[n*36+k]
            const short* r0 = Hb + (size_t)(kb + 2 * bkp) * N_ + nb + bn;
#pragma unroll
            for (int p = 0; p < 8; p++) {
                const unsigned ra = *(const unsigned*)(r0 + 32 * p);
                const unsigned rb = *(const unsigned*)(r0 + 32 * p + N_);
                *(unsigned*)&Bs[(bn + 32 * p) * 36 + 2 * bkp] = (ra & 0xffffu) | (rb << 16);
                *(unsigned*)&Bs[(bn + 1 + 32 * p) * 36 + 2 * bkp] = (ra >> 16) | (rb & 0xffff0000u);
            }
        }
        __syncthreads();
        bf16x8 af[4], bv[4];
#pragma unroll
        for (int mi = 0; mi < 4; mi++) af[mi] = ldfrag(&As[(mi * 16 + fr) * 36 + fg * 8]);
#pragma unroll
        for (int ni = 0; ni < 4; ni++) bv[ni] = ldfrag(&Bs[(wave * 64 + ni * 16 + fr) * 36 + fg * 8]);
#pragma unroll
        for (int mi = 0; mi < 4; mi++)
#pragma unroll
            for (int ni = 0; ni < 4; ni++)
                accN[mi][ni] = mfma16(af[mi], bv[ni], accN[mi][ni]);
        __syncthreads();
    }

    f32x4 accD[4][4];
    if (UPDATE) {
        for (int i = 0; i < 4; i++) for (int j = 0; j < 4; j++) accD[i][j] = zero4;
        {   // stage btb [64][64] -> Ds (stride 68)
            const short* bt = btb + bb * R_ * R_;
#pragma unroll
            for (int i = 0; i < 2; i++) {
                const int row = t & 63, kc8 = ((t >> 6) + 4 * i) * 8;
                const short* src = bt + row * 64 + kc8;
                short* dst = &Ds[row * 68 + kc8];
                *(bf16x4*)dst = *(const bf16x4*)src;
                *(bf16x4*)(dst + 4) = *(const bf16x4*)(src + 4);
            }
        }
        // phase 2: den = btb @ coef, two K=32 substeps reusing Bs
        for (int ks = 0; ks < 2; ks++) {
            const short* r0 = coefB + (size_t)(ks * 32 + 2 * bkp) * N_ + nb + bn;
#pragma unroll
            for (int p = 0; p < 8; p++) {
                const unsigned ra = *(const unsigned*)(r0 + 32 * p);
                const unsigned rb = *(const unsigned*)(r0 + 32 * p + N_);
                *(unsigned*)&Bs[(bn + 32 * p) * 36 + 2 * bkp] = (ra & 0xffffu) | (rb << 16);
                *(unsigned*)&Bs[(bn + 1 + 32 * p) * 36 + 2 * bkp] = (ra >> 16) | (rb & 0xffff0000u);
            }
            __syncthreads();
            bf16x8 af[4], bv[4];
#pragma unroll
            for (int mi = 0; mi < 4; mi++) af[mi] = ldfrag(&Ds[(mi * 16 + fr) * 68 + ks * 32 + fg * 8]);
#pragma unroll
            for (int ni = 0; ni < 4; ni++) bv[ni] = ldfrag(&Bs[(wave * 64 + ni * 16 + fr) * 36 + fg * 8]);
#pragma unroll
            for (int mi = 0; mi < 4; mi++)
#pragma unroll
                for (int ni = 0; ni < 4; ni++)
                    accD[mi][ni] = mfma16(af[mi], bv[ni], accD[mi][ni]);
            __syncthreads();
        }
        // phase 3: multiplicative update
#pragma unroll
        for (int mi = 0; mi < 4; mi++)
#pragma unroll
            for (int ni = 0; ni < 4; ni++)
#pragma unroll
                for (int j = 0; j < 4; j++) {
                    const int m = mi * 16 + fg * 4 + j;
                    const int n = nb + wave * 64 + ni * 16 + fr;
                    short* p = coefB + (size_t)m * N_ + n;
                    float oldv = bf2f(*p);
                    float nv = oldv * accN[mi][ni][j] / (accD[mi][ni][j] + EPS);
                    *p = f2bf(nv);
                }
    } else {
        // softmax over r per column
#pragma unroll
        for (int ni = 0; ni < 4; ni++) {
            float mx = -3e38f;
#pragma unroll
            for (int mi = 0; mi < 4; mi++)
#pragma unroll
                for (int j = 0; j < 4; j++) mx = fmaxf(mx, accN[mi][ni][j]);
            mx = fmaxf(mx, __shfl_xor(mx, 16, 64));
            mx = fmaxf(mx, __shfl_xor(mx, 32, 64));
            float sm = 0.f;
#pragma unroll
            for (int mi = 0; mi < 4; mi++)
#pragma unroll
                for (int j = 0; j < 4; j++) {
                    float e = __expf(accN[mi][ni][j] - mx);
                    accN[mi][ni][j] = e;
                    sm += e;
                }
            sm += __shfl_xor(sm, 16, 64);
            sm += __shfl_xor(sm, 32, 64);
            const float inv = 1.f / sm;
#pragma unroll
            for (int mi = 0; mi < 4; mi++)
#pragma unroll
                for (int j = 0; j < 4; j++) {
                    const int m = mi * 16 + fg * 4 + j;
                    const int n = nb + wave * 64 + ni * 16 + fr;
                    coefB[(size_t)m * N_ + n] = f2bf(accN[mi][ni][j] * inv);
                }
        }
    }
}

// ---------------------------------------------------------------------------
// k_tn: C[r][dd] = sum_k A[r,k]*B[dd,k]  (TN GEMM, stride-68 tiles)
// MODE 0: A=coef, B=[H ; coef] rows (576), split-K -> f32 partials
// MODE 1: A=B=basesT -> btb bf16
// MODE 2: A=basesT, B=Wout(f32) -> Wfused bf16 stored [o][r]
// ---------------------------------------------------------------------------
template<int MODE>
__global__ __launch_bounds__(256)
void k_tn(const short* __restrict__ coef, const short* __restrict__ Hh,
          const short* __restrict__ basesTb, const float* __restrict__ Wout,
          float* __restrict__ parts, short* __restrict__ btb, short* __restrict__ wf) {
    const int ddt = blockIdx.x, ch = blockIdx.y, bb = blockIdx.z;
    const int kLen = (MODE == 0) ? 2048 : 512;
    const int k0g = ch * kLen;
    const short* Ap; int lda;
    if (MODE == 0) { Ap = coef + (size_t)bb * R_ * N_; lda = N_; }
    else           { Ap = basesTb + (size_t)bb * R_ * C_; lda = C_; }
    __shared__ short As[64 * 68];
    __shared__ short Bs[64 * 68];
    const int t = threadIdx.x;
    const int lane = t & 63, wave = t >> 6;
    const int fr = lane & 15, fg = lane >> 4;
    f32x4 zero4 = {0.f, 0.f, 0.f, 0.f};
    f32x4 acc[4];
    for (int i = 0; i < 4; i++) acc[i] = zero4;

    for (int kb = 0; kb < kLen; kb += 64) {
#pragma unroll
        for (int i = 0; i < 2; i++) {   // stage A
            const int kg = (t & 7) * 8, row = (t >> 3) + 32 * i;
            const short* src = Ap + (size_t)row * lda + k0g + kb + kg;
            short* dst = &As[row * 68 + kg];
            *(bf16x4*)dst = *(const bf16x4*)src;
            *(bf16x4*)(dst + 4) = *(const bf16x4*)(src + 4);
        }
#pragma unroll
        for (int i = 0; i < 2; i++) {   // stage B
            const int kg = (t & 7) * 8, row = (t >> 3) + 32 * i;
            const int dd = ddt * 64 + row;
            short* dst = &Bs[row * 68 + kg];
            if (MODE == 2) {
                const float* src = Wout + (size_t)dd * C_ + kb + kg;
                float4 v0 = *(const float4*)src;
                float4 v1 = *(const float4*)(src + 4);
                *(unsigned*)dst = pk2(v0.x, v0.y);
                *(unsigned*)(dst + 2) = pk2(v0.z, v0.w);
                *(unsigned*)(dst + 4) = pk2(v1.x, v1.y);
                *(unsigned*)(dst + 6) = pk2(v1.z, v1.w);
            } else {
                const short* src;
                if (MODE == 0)
                    src = (dd < C_) ? Hh + (size_t)bb * C_ * N_ + (size_t)dd * N_ + k0g + kb + kg
                                    : coef + (size_t)bb * R_ * N_ + (size_t)(dd - C_) * N_ + k0g + kb + kg;
                else
                    src = basesTb + (size_t)bb * R_ * C_ + (size_t)dd * C_ + kb + kg;
                *(bf16x4*)dst = *(const bf16x4*)src;
                *(bf16x4*)(dst + 4) = *(const bf16x4*)(src + 4);
            }
        }
        __syncthreads();
#pragma unroll
        for (int kk = 0; kk < 2; kk++) {
            bf16x8 a = ldfrag(&As[(wave * 16 + fr) * 68 + kk * 32 + fg * 8]);
#pragma unroll
            for (int ni = 0; ni < 4; ni++) {
                bf16x8 b = ldfrag(&Bs[(ni * 16 + fr) * 68 + kk * 32 + fg * 8]);
                acc[ni] = mfma16(a, b, acc[ni]);
            }
        }
        __syncthreads();
    }
#pragma unroll
    for (int ni = 0; ni < 4; ni++)
#pragma unroll
        for (int j = 0; j < 4; j++) {
            const int r = wave * 16 + fg * 4 + j;
            const int dd = ddt * 64 + ni * 16 + fr;
            if (MODE == 0)
                parts[(((size_t)bb * 8 + ch) * 64 + r) * 576 + dd] = acc[ni][j];
            else if (MODE == 1)
                btb[bb * R_ * R_ + r * 64 + dd] = f2bf(acc[ni][j]);
            else
                wf[(size_t)bb * C_ * R_ + (size_t)dd * 64 + r] = f2bf(acc[ni][j]);
        }
}

// ---------------------------------------------------------------------------
// k_bases_update
// ---------------------------------------------------------------------------
__global__ __launch_bounds__(256)
void k_bases_update(const float* __restrict__ parts, float* __restrict__ basesT,
                    short* __restrict__ basesTb) {
    const int dt = blockIdx.x, bb = blockIdx.y;
    __shared__ float ctcL[64 * 64];
    const int t = threadIdx.x;
    for (int idx = t; idx < 4096; idx += 256) {
        const int r = idx >> 6, s = idx & 63;
        float sum = 0.f;
#pragma unroll
        for (int ch = 0; ch < 8; ch++)
            sum += parts[(((size_t)bb * 8 + ch) * 64 + r) * 576 + 512 + s];
        ctcL[idx] = sum;
    }
    __syncthreads();
    float nv[16];
#pragma unroll
    for (int i = 0; i < 16; i++) {
        const int idx = t + i * 256;
        const int r = idx >> 6, d = dt * 64 + (idx & 63);
        float num = 0.f;
#pragma unroll
        for (int ch = 0; ch < 8; ch++)
            num += parts[(((size_t)bb * 8 + ch) * 64 + r) * 576 + d];
        float den = 0.f;
        const float* bcol = basesT + (size_t)bb * R_ * C_ + d;
        for (int s = 0; s < 64; s++)
            den += ctcL[r * 64 + s] * bcol[(size_t)s * C_];
        const float oldv = basesT[(size_t)bb * R_ * C_ + (size_t)r * C_ + d];
        nv[i] = oldv * num / (den + EPS);
    }
    __syncthreads();
#pragma unroll
    for (int i = 0; i < 16; i++) {
        const int idx = t + i * 256;
        const int r = idx >> 6, d = dt * 64 + (idx & 63);
        basesT[(size_t)bb * R_ * C_ + (size_t)r * C_ + d] = nv[i];
        basesTb[(size_t)bb * R_ * C_ + (size_t)r * C_ + d] = f2bf(nv[i]);
    }
}

// ---------------------------------------------------------------------------
// k_final: out = relu(x + Wfused @ coef + b_out)   (K=64), stride-68 tiles
// ---------------------------------------------------------------------------
__global__ __launch_bounds__(256)
void k_final(const short* __restrict__ wf, const short* __restrict__ coef,
             const float* __restrict__ X, const float* __restrict__ bias,
             float* __restrict__ out) {
    const int nb = blockIdx.x * 128, mb = blockIdx.y * 128, bb = blockIdx.z;
    __shared__ short As[128 * 68];
    __shared__ short Bs[128 * 68];
    const int t = threadIdx.x;
    const int lane = t & 63, wave = t >> 6;
    const int wm = wave >> 1, wn = wave & 1;
    const int fr = lane & 15, fg = lane >> 4;
    const short* wfb = wf + (size_t)bb * C_ * R_;
    const short* coefB = coef + (size_t)bb * R_ * N_;
    f32x4 zero4 = {0.f, 0.f, 0.f, 0.f};
    f32x4 acc[4][4];
    for (int i = 0; i < 4; i++) for (int j = 0; j < 4; j++) acc[i][j] = zero4;

#pragma unroll
    for (int i = 0; i < 4; i++) {   // stage A = Wfused [128 rows][64]
        const int kg = (t & 7) * 8, row = (t >> 3) + 32 * i;
        const short* src = wfb + (size_t)(mb + row) * 64 + kg;
        short* dst = &As[row * 68 + kg];
        *(bf16x4*)dst = *(const bf16x4*)src;
        *(bf16x4*)(dst + 4) = *(const bf16x4*)(src + 4);
    }
    {   // stage B transposed: coef[k][n] -> Bs[n*68+k]; lane pairs of n, kp spread
        const int bn = 2 * (t & 15), bkp = t >> 4;     // bkp 0..15, plus 16*i
#pragma unroll
        for (int i = 0; i < 2; i++) {
            const int kp = bkp + 16 * i;
            const short* r0 = coefB + (size_t)(2 * kp) * N_ + nb + bn;
#pragma unroll
            for (int p = 0; p < 4; p++) {
                const unsigned ra = *(const unsigned*)(r0 + 32 * p);
                const unsigned rb = *(const unsigned*)(r0 + 32 * p + N_);
                *(unsigned*)&Bs[(bn + 32 * p) * 68 + 2 * kp] = (ra & 0xffffu) | (rb << 16);
                *(unsigned*)&Bs[(bn + 1 + 32 * p) * 68 + 2 * kp] = (ra >> 16) | (rb & 0xffff0000u);
            }
        }
    }
    __syncthreads();
#pragma unroll
    for (int kk = 0; kk < 2; kk++) {
        bf16x8 af[4], bv[4];
#pragma unroll
        for (int mi = 0; mi < 4; mi++) af[mi] = ldfrag(&As[(wm * 64 + mi * 16 + fr) * 68 + kk * 32 + fg * 8]);
#pragma unroll
        for (int ni = 0; ni < 4; ni++) bv[ni] = ldfrag(&Bs[(wn * 64 + ni * 16 + fr) * 68 + kk * 32 + fg * 8]);
#pragma unroll
        for (int mi = 0; mi < 4; mi++)
#pragma unroll
            for (int ni = 0; ni < 4; ni++)
                acc[mi][ni] = mfma16(af[mi], bv[ni], acc[mi][ni]);
    }
    const float* Xb = X + (size_t)bb * C_ * N_;
    float* Ob = out + (size_t)bb * C_ * N_;
#pragma unroll
    for (int mi = 0; mi < 4; mi++)
#pragma unroll
        for (int j = 0; j < 4; j++) {
            const int m = mb + wm * 64 + mi * 16 + fg * 4 + j;
            const float bvv = bias[m];
            const float* xrow = Xb + (size_t)m * N_ + nb;
            float* orow = Ob + (size_t)m * N_ + nb;
#pragma unroll
            for (int ni = 0; ni < 4; ni++) {
                const int n = wn * 64 + ni * 16 + fr;
                float v = xrow[n] + acc[mi][ni][j] + bvv;
                orow[n] = v > 0.f ? v : 0.f;
            }
        }
}

// ---------------------------------------------------------------------------
extern "C" void kernel_launch(void* const* d_in, const int* in_sizes, int n_in,
                              void* d_out, int out_size, void* d_ws, size_t ws_size,
                              hipStream_t stream) {
    const float* x     = (const float*)d_in[0];
    const float* w_in  = (const float*)d_in[1];
    const float* b_in  = (const float*)d_in[2];
    const float* w_out = (const float*)d_in[3];
    const float* b_out = (const float*)d_in[4];
    const float* bases = (const float*)d_in[5];
    float* out = (float*)d_out;

    short* h       = (short*)d_ws;                     // 67108864 shorts (134.2 MB)
    short* coef    = h + (size_t)67108864;             // 8388608 shorts (16.8 MB)
    float* basesT  = (float*)(coef + 8388608);         // 262144 floats (1 MB)
    short* basesTb = (short*)(basesT + 262144);        // 262144 shorts
    short* btb     = basesTb + 262144;                 // 32768 shorts
    short* wf      = btb + 32768;                      // 262144 shorts
    float* parts   = (float*)(wf + 262144);            // 2359296 floats (9.4 MB)
    short* wbf     = (short*)(parts + 2359296);        // 262144 shorts (0.5 MB)

    k_prep<<<1024, 256, 0, stream>>>(bases, basesT, basesTb, w_in, wbf);
    k_conv1<<<dim3(128, 4, 8), 256, 0, stream>>>(wbf, b_in, x, h);
    k_coef<0><<<dim3(64, 8), 256, 0, stream>>>(basesTb, h, btb, coef);
    for (int s = 0; s < 7; s++) {
        k_tn<1><<<dim3(1, 1, 8), 256, 0, stream>>>(coef, h, basesTb, w_out, parts, btb, wf);
        k_coef<1><<<dim3(64, 8), 256, 0, stream>>>(basesTb, h, btb, coef);
        k_tn<0><<<dim3(9, 8, 8), 256, 0, stream>>>(coef, h, basesTb, w_out, parts, btb, wf);
        k_bases_update<<<dim3(8, 8), 256, 0, stream>>>(parts, basesT, basesTb);
    }
    k_tn<1><<<dim3(1, 1, 8), 256, 0, stream>>>(coef, h, basesTb, w_out, parts, btb, wf);
    k_coef<1><<<dim3(64, 8), 256, 0, stream>>>(basesTb, h, btb, coef);
    k_tn<2><<<dim3(8, 1, 8), 256, 0, stream>>>(coef, h, basesTb, w_out, parts, btb, wf);
    k_final<<<dim3(128, 4, 8), 256, 0, stream>>>(wf, coef, x, b_out, out);
}